// Round 4
// baseline (273.155 us; speedup 1.0000x reference)
//
#include <hip/hip_runtime.h>

#define N_SERIES 2048
#define N_TIME 4096
#define SEAS 7
#define EMB 9
#define INPUT_SIZE 28
#define OUTPUT_SIZE 7

#define OUT0_N (OUTPUT_SIZE * N_SERIES * INPUT_SIZE)   // 401408  windows_y_hat
#define OUT1_N (OUTPUT_SIZE * N_SERIES * OUTPUT_SIZE)  // 100352  windows_y (zeros)
#define LEV_N  (N_SERIES * N_TIME)                     // 8388608 levels
#define SEA_N  (N_SERIES * (N_TIME + SEAS))            // 8403968 seasonalities

#define T_TILE 63      // multiple of 7 -> static season-ring slots; 63*65 = 4095
#define N_TILES 65
#define ROWS 64        // series per block
#define YSTRIDE 65     // row stride (dwords): bank = (lane+u)%32 -> 2/bank free

__device__ __forceinline__ float rcp_(float x) { return __builtin_amdgcn_rcpf(x); }

// async global->LDS, 4B per lane, dest = ldsbase + lane*4 (contiguous)
#define GLD_LDS(gp, lp)                                                        \
    __builtin_amdgcn_global_load_lds(                                          \
        (const __attribute__((address_space(1))) unsigned int*)(gp),           \
        (__attribute__((address_space(3))) unsigned int*)(lp), 4, 0, 0)

// 2 waves/block, 64 series/block, 32 blocks.
// wave0 = scanner: pure LDS+VALU sequential ES recurrence.
// wave1 = staging: global_load_lds prefetch of y tile k+1 (async, no VGPRs),
//         then coalesced writeback of lev/sea tile k-1.
__global__ __launch_bounds__(128) void es_scan(
    const float* __restrict__ y,
    const int* __restrict__ idxs,
    const float* __restrict__ emb,
    float* __restrict__ levels,
    float* __restrict__ seas_out)
{
    __shared__ float ly[2][ROWS][YSTRIDE];    // y:   [buf][series][time]
    __shared__ float llev[2][ROWS][YSTRIDE];  // lev: [buf][series][time]
    __shared__ float lsea[2][ROWS][YSTRIDE];  // sea: [buf][series][time]

    const int lane = threadIdx.x & 63;
    const int wid  = threadIdx.x >> 6;
    const int s0   = blockIdx.x * ROWS;

    // scanner state (wave 0 only)
    float sea_r[SEAS], rsl[SEAS];
    float level = 0.f, oml = 0.f, oms = 0.f, lev_sms = 0.f, seas_sms = 0.f;

    if (wid == 0) {
        const int s = s0 + lane;
        const int idx = idxs[s];
        const float* e = emb + (size_t)idx * EMB;
        lev_sms  = 1.0f / (1.0f + expf(-e[0]));
        seas_sms = 1.0f / (1.0f + expf(-e[1]));
        oml = 1.0f - lev_sms;
        oms = 1.0f - seas_sms;
        float* sr = seas_out + (size_t)s * (N_TIME + SEAS);
#pragma unroll
        for (int j = 0; j < SEAS; ++j) {
            float v = expf(e[2 + j]);
            sea_r[j] = v;
            rsl[j] = lev_sms * rcp_(v);
            sr[j] = v;                       // seasonalities[0..6] = init
        }
        sr[SEAS] = sea_r[0];                 // seasonalities[7] = init[0]
        level = y[(size_t)s * N_TIME] * rcp_(sea_r[0]);
        levels[(size_t)s * N_TIME] = level;
    } else {
        // prologue: async-load tile 0 (t = 1..63, +1 junk) into buffer 0
#pragma unroll 8
        for (int r = 0; r < ROWS; ++r)
            GLD_LDS(&y[(size_t)(s0 + r) * N_TIME + 1 + lane], &ly[0][r][0]);
    }
    __syncthreads();

    for (int k = 0; k < N_TILES; ++k) {
        const int cur = k & 1;
        if (wid == 0) {
            // scan tile k: t = 1+63k+u, u=0..62; slot = (1+u)%7 is static
            const float* yrow = &ly[cur][lane][0];
            float* lrow = &llev[cur][lane][0];
            float* srow = &lsea[cur][lane][0];
            for (int g = 0; g < 9; ++g) {
#pragma unroll
                for (int j = 0; j < 7; ++j) {
                    const int u = g * 7 + j;
                    const int slot = (1 + j) % SEAS;
                    float yt = yrow[u];
                    float nl = fmaf(oml, level, yt * rsl[slot]);
                    float r  = rcp_(nl);
                    float ns = fmaf(oms, sea_r[slot], (seas_sms * yt) * r);
                    sea_r[slot] = ns;
                    rsl[slot] = lev_sms * rcp_(ns);
                    lrow[u] = nl;
                    srow[u] = ns;
                    level = nl;
                }
            }
        } else {
            // 1) async prefetch y tile k+1 into ly[cur^1] (fire-and-forget)
            if (k + 1 < N_TILES) {
                const int tn = 1 + (k + 1) * T_TILE;
                int t = tn + lane;
                if (t > N_TIME - 1) t = N_TIME - 1;   // tail guard (junk lane)
#pragma unroll 8
                for (int r = 0; r < ROWS; ++r)
                    GLD_LDS(&y[(size_t)(s0 + r) * N_TIME + t], &ly[cur ^ 1][r][0]);
            }
            // 2) coalesced writeback of lev/sea tile k-1 from buf cur^1
            if (k >= 1 && lane < T_TILE) {
                const int tp = 1 + (k - 1) * T_TILE;
                for (int r = 0; r < ROWS; ++r) {
                    const size_t s = s0 + r;
                    levels[s * N_TIME + tp + lane] = llev[cur ^ 1][r][lane];
                    seas_out[s * (N_TIME + SEAS) + SEAS + tp + lane] =
                        lsea[cur ^ 1][r][lane];
                }
            }
        }
        __syncthreads();   // drains wave1's vmcnt -> prefetched tile published
    }

    // epilogue: store tile 64 (buffer 0); rows split across the 2 waves
    {
        const int tp = 1 + (N_TILES - 1) * T_TILE;       // 4033
        if (lane < T_TILE) {
            for (int r = wid * 32; r < wid * 32 + 32; ++r) {
                const size_t s = s0 + r;
                levels[s * N_TIME + tp + lane] = llev[0][r][lane];
                seas_out[s * (N_TIME + SEAS) + SEAS + tp + lane] =
                    lsea[0][r][lane];
            }
        }
    }
}

// windows_y_hat = log(y / lev / seas) transposed to (w, s, i); zero windows_y.
__global__ __launch_bounds__(256) void es_windows(
    const float* __restrict__ y,
    const float* __restrict__ levels,
    const float* __restrict__ seas,
    float* __restrict__ out0,
    float* __restrict__ out1)
{
    int tid = blockIdx.x * 256 + threadIdx.x;
    if (tid < OUT0_N) {
        int i = tid % INPUT_SIZE;
        int r = tid / INPUT_SIZE;
        int s = r & (N_SERIES - 1);
        int w = r >> 11;
        int t = (N_TIME - INPUT_SIZE - OUTPUT_SIZE + 1) + w + i;     // 4062+w+i
        float yt = y[(size_t)s * N_TIME + t];
        float lv = levels[(size_t)s * N_TIME + (N_TIME - OUTPUT_SIZE + w)];
        float sv = seas[(size_t)s * (N_TIME + SEAS) + t];
        float ratio = yt * rcp_(lv * sv);
        out0[tid] = __builtin_amdgcn_logf(ratio) * 0.6931471805599453f;
    } else {
        int j = tid - OUT0_N;
        if (j < OUT1_N) out1[j] = 0.0f;
    }
}

extern "C" void kernel_launch(void* const* d_in, const int* in_sizes, int n_in,
                              void* d_out, int out_size, void* d_ws, size_t ws_size,
                              hipStream_t stream) {
    const float* y    = (const float*)d_in[0];
    const int*   idxs = (const int*)d_in[1];
    const float* emb  = (const float*)d_in[2];

    float* out  = (float*)d_out;
    float* out0 = out;                           // windows_y_hat
    float* out1 = out + OUT0_N;                  // windows_y (zeros)
    float* lev  = out + OUT0_N + OUT1_N;         // levels
    float* sea  = out + OUT0_N + OUT1_N + LEV_N; // seasonalities

    es_scan<<<32, 128, 0, stream>>>(y, idxs, emb, lev, sea);
    es_windows<<<(OUT0_N + OUT1_N) / 256, 256, 0, stream>>>(y, lev, sea, out0, out1);
}

// Round 6
// 159.876 us; speedup vs baseline: 1.7085x; 1.7085x over previous
//
#include <hip/hip_runtime.h>

#define N_SERIES 2048
#define N_TIME   4096
#define SEAS     7
#define EMB      9
#define INPUT_SIZE 28
#define OUTPUT_SIZE 7

#define OUT0_N (OUTPUT_SIZE * N_SERIES * INPUT_SIZE)   // 401408  windows_y_hat
#define OUT1_N (OUTPUT_SIZE * N_SERIES * OUTPUT_SIZE)  // 100352  windows_y (zeros)
#define LEV_N  (N_SERIES * N_TIME)                     // levels
#define SEA_N  (N_SERIES * (N_TIME + SEAS))            // seasonalities

#define LCH  112        // main steps owned per chunk (16*7)
#define WUP  224        // guess-warmup steps (32 season cycles)
#define NCH  37         // chunks: t0(c) = 1 + 112c; c=36 owns 4033..4095
#define TT   56         // tile steps (8*7 -> season slot j is static)
#define PADS 65         // [time][series] LDS stride: banks (lane+r)%32 -> 2-way (free)
#define WSP  (NCH * N_SERIES)   // ws plane stride (floats)
// ws planes: 0=level, 1..7=ring, 8=A(sum log2 ring@chunk end), 9=B(@t0), 10=kappa

__device__ __forceinline__ float rcp_(float x){ return __builtin_amdgcn_rcpf(x); }
__device__ __forceinline__ float log2_(float x){ return __builtin_amdgcn_logf(x); }

// ---------- Stage A: chunked warmup scan, emit scale anchors + state ----------
// c==0: exact main only (2 tiles). c==1: exact 112 warmup + main (4 tiles).
// c==2: exact 224 warmup + main (6 tiles). c>=3: guessed 224 warmup + main (6).
__global__ __launch_bounds__(64) void es_stageA(
    const float* __restrict__ y, const int* __restrict__ idxs,
    const float* __restrict__ emb, float* __restrict__ ws)
{
    __shared__ float ly[TT][PADS];
    const int lane = threadIdx.x;
    const int c = blockIdx.x % NCH, g = blockIdx.x / NCH;
    const int s0 = g * 64, s = s0 + lane;
    const int t0 = 1 + c * LCH;
    const bool exact = (c <= 2);
    const int tw = exact ? 1 : (t0 - WUP);
    const int ntiles = (c == 0) ? 2 : ((c == 1) ? 4 : 6);
    const int save_tt = (c == 1) ? 1 : 3;    // tile after which state@t0 is saved

    const float* e = emb + (size_t)idxs[s] * EMB;
    const float lev_sms  = 1.f / (1.f + expf(-e[0]));
    const float seas_sms = 1.f / (1.f + expf(-e[1]));
    const float oml = 1.f - lev_sms, oms = 1.f - seas_sms;

    float ring[7], rsl[7], level;
    if (exact) {
        float einit[7];
#pragma unroll
        for (int j = 0; j < 7; ++j) einit[j] = expf(e[2 + j]);
#pragma unroll
        for (int j = 0; j < 7; ++j) ring[j] = einit[(1 + j) % 7]; // slot j ~ t=(1+j)%7
        level = y[(size_t)s * N_TIME] * rcp_(einit[0]);
    } else {
#pragma unroll
        for (int j = 0; j < 7; ++j) ring[j] = 1.64872127f;   // exp(0.5) prior
        level = y[(size_t)s * N_TIME + (tw - 1)] * 0.60653066f;
    }
#pragma unroll
    for (int j = 0; j < 7; ++j) rsl[j] = lev_sms * rcp_(ring[j]);

    float svlev = 1.f, svring[7];
#pragma unroll
    for (int j = 0; j < 7; ++j) svring[j] = 1.f;

    for (int tt = 0; tt < ntiles; ++tt) {
        const int tb = tw + tt * TT;
        // stage y[64 rows][56 cols] -> LDS [time][series] (coalesced-ish per row)
#pragma unroll 8
        for (int r = 0; r < 64; ++r) {
            if (lane < TT) {
                int t = tb + lane; if (t > N_TIME - 1) t = N_TIME - 1;
                ly[lane][r] = y[(size_t)(s0 + r) * N_TIME + t];
            }
        }
        // scan 56 steps; k%7==j static (TT multiple of 7, tb ≡ 1 mod 7)
        for (int g8 = 0; g8 < 8; ++g8) {
#pragma unroll
            for (int j = 0; j < 7; ++j) {
                const int k = g8 * 7 + j;
                float yt = ly[k][lane];
                float nl = fmaf(oml, level, yt * rsl[j]);
                float rl = rcp_(nl);
                float ns = fmaf(oms, ring[j], (seas_sms * yt) * rl);
                ring[j] = ns;
                rsl[j]  = lev_sms * rcp_(ns);
                level = nl;
            }
        }
        if (c != 0 && tt == save_tt) {   // state entering step t0
            svlev = level;
#pragma unroll
            for (int j = 0; j < 7; ++j) svring[j] = ring[j];
        }
    }

    float A = 0.f;
#pragma unroll
    for (int j = 0; j < 7; ++j) A += log2_(ring[j]);
    ws[8 * WSP + c * N_SERIES + s] = A;
    if (c != 0) {
        float B = 0.f;
#pragma unroll
        for (int j = 0; j < 7; ++j) B += log2_(svring[j]);
        ws[9 * WSP + c * N_SERIES + s] = B;
        ws[0 * WSP + c * N_SERIES + s] = svlev;
#pragma unroll
        for (int j = 0; j < 7; ++j)
            ws[(1 + j) * WSP + c * N_SERIES + s] = svring[j];
    }
}

// ---------- Chain: per-series kappa recurrence over 37 chunks ----------
__global__ __launch_bounds__(64) void es_chain(float* __restrict__ ws)
{
    const int s = blockIdx.x * 64 + threadIdx.x;   // grid 32 blocks
    float kap = 0.f;
    ws[10 * WSP + 0 * N_SERIES + s] = 0.f;
    float Aprev = ws[8 * WSP + 0 * N_SERIES + s];
    for (int c = 1; c < NCH; ++c) {
        float B = ws[9 * WSP + c * N_SERIES + s];
        kap += (Aprev - B) * (1.f / 7.f);
        ws[10 * WSP + c * N_SERIES + s] = kap;
        Aprev = ws[8 * WSP + c * N_SERIES + s];
    }
}

// ---------- Stage C: rescaled re-scan of owned 112 steps, store outputs ----------
__global__ __launch_bounds__(64) void es_stageC(
    const float* __restrict__ y, const int* __restrict__ idxs,
    const float* __restrict__ emb, const float* __restrict__ ws,
    float* __restrict__ levels, float* __restrict__ seas_out)
{
    __shared__ float ly[TT][PADS], llev[TT][PADS], lsea[TT][PADS];
    const int lane = threadIdx.x;
    const int c = blockIdx.x % NCH, g = blockIdx.x / NCH;
    const int s0 = g * 64, s = s0 + lane;
    const int t0 = 1 + c * LCH;

    const float* e = emb + (size_t)idxs[s] * EMB;
    const float lev_sms  = 1.f / (1.f + expf(-e[0]));
    const float seas_sms = 1.f / (1.f + expf(-e[1]));
    const float oml = 1.f - lev_sms, oms = 1.f - seas_sms;

    float ring[7], rsl[7], level;
    if (c == 0) {
        float einit[7];
#pragma unroll
        for (int j = 0; j < 7; ++j) einit[j] = expf(e[2 + j]);
#pragma unroll
        for (int j = 0; j < 7; ++j) ring[j] = einit[(1 + j) % 7];
        level = y[(size_t)s * N_TIME] * rcp_(einit[0]);
        levels[(size_t)s * N_TIME] = level;              // levels[:,0]
        float* sr = seas_out + (size_t)s * (N_TIME + SEAS);
#pragma unroll
        for (int j = 0; j < 7; ++j) sr[j] = einit[j];    // seasonalities[:,0..6]
        sr[7] = einit[0];                                // seasonalities[:,7]
    } else {
        float kap = ws[10 * WSP + c * N_SERIES + s];
        float f  = exp2f(kap);     // true_sea = our_sea * 2^kappa
        float fi = exp2f(-kap);    // true_lev = our_lev * 2^-kappa
        level = ws[0 * WSP + c * N_SERIES + s] * fi;
#pragma unroll
        for (int j = 0; j < 7; ++j)
            ring[j] = ws[(1 + j) * WSP + c * N_SERIES + s] * f;
    }
#pragma unroll
    for (int j = 0; j < 7; ++j) rsl[j] = lev_sms * rcp_(ring[j]);

    for (int tt = 0; tt < 2; ++tt) {
        const int tb = t0 + tt * TT;
        // stage y
#pragma unroll 8
        for (int r = 0; r < 64; ++r) {
            if (lane < TT) {
                int t = tb + lane; if (t > N_TIME - 1) t = N_TIME - 1;
                ly[lane][r] = y[(size_t)(s0 + r) * N_TIME + t];
            }
        }
        // scan 56 steps, record lev/sea into LDS
        for (int g8 = 0; g8 < 8; ++g8) {
#pragma unroll
            for (int j = 0; j < 7; ++j) {
                const int k = g8 * 7 + j;
                float yt = ly[k][lane];
                float nl = fmaf(oml, level, yt * rsl[j]);
                float rl = rcp_(nl);
                float ns = fmaf(oms, ring[j], (seas_sms * yt) * rl);
                ring[j] = ns;
                rsl[j]  = lev_sms * rcp_(ns);
                llev[k][lane] = nl;
                lsea[k][lane] = ns;
                level = nl;
            }
        }
        // transpose-writeback: coalesced stores along time
        if (lane < TT) {
            const int t = tb + lane;
            if (t <= N_TIME - 1) {
#pragma unroll 8
                for (int r = 0; r < 64; ++r) {
                    levels[(size_t)(s0 + r) * N_TIME + t] = llev[lane][r];
                    seas_out[(size_t)(s0 + r) * (N_TIME + SEAS) + SEAS + t] = lsea[lane][r];
                }
            }
        }
    }
}

// ---------- windows_y_hat + zero windows_y ----------
__global__ __launch_bounds__(256) void es_windows(
    const float* __restrict__ y,
    const float* __restrict__ levels,
    const float* __restrict__ seas,
    float* __restrict__ out0,
    float* __restrict__ out1)
{
    int tid = blockIdx.x * 256 + threadIdx.x;
    if (tid < OUT0_N) {
        int i = tid % INPUT_SIZE;
        int r = tid / INPUT_SIZE;
        int s = r & (N_SERIES - 1);
        int w = r >> 11;
        int t = (N_TIME - INPUT_SIZE - OUTPUT_SIZE + 1) + w + i;     // 4062+w+i
        float yt = y[(size_t)s * N_TIME + t];
        float lv = levels[(size_t)s * N_TIME + (N_TIME - OUTPUT_SIZE + w)];
        float sv = seas[(size_t)s * (N_TIME + SEAS) + t];
        float ratio = yt * rcp_(lv * sv);
        out0[tid] = log2_(ratio) * 0.6931471805599453f;   // ln = log2 * ln2
    } else {
        int j = tid - OUT0_N;
        if (j < OUT1_N) out1[j] = 0.0f;
    }
}

extern "C" void kernel_launch(void* const* d_in, const int* in_sizes, int n_in,
                              void* d_out, int out_size, void* d_ws, size_t ws_size,
                              hipStream_t stream) {
    const float* y    = (const float*)d_in[0];
    const int*   idxs = (const int*)d_in[1];
    const float* emb  = (const float*)d_in[2];

    float* out  = (float*)d_out;
    float* out0 = out;                           // windows_y_hat
    float* out1 = out + OUT0_N;                  // windows_y (zeros)
    float* lev  = out + OUT0_N + OUT1_N;         // levels
    float* sea  = out + OUT0_N + OUT1_N + LEV_N; // seasonalities
    float* ws   = (float*)d_ws;                  // 11 planes * 37*2048 floats ≈ 3.3 MB

    es_stageA<<<32 * NCH, 64, 0, stream>>>(y, idxs, emb, ws);
    es_chain<<<N_SERIES / 64, 64, 0, stream>>>(ws);
    es_stageC<<<32 * NCH, 64, 0, stream>>>(y, idxs, emb, ws, lev, sea);
    es_windows<<<(OUT0_N + OUT1_N) / 256, 256, 0, stream>>>(y, lev, sea, out0, out1);
}

// Round 8
// 142.482 us; speedup vs baseline: 1.9171x; 1.1221x over previous
//
#include <hip/hip_runtime.h>

#define N_SERIES 2048
#define N_TIME   4096
#define SEAS     7
#define EMB      9
#define INPUT_SIZE 28
#define OUTPUT_SIZE 7

#define OUT0_N (OUTPUT_SIZE * N_SERIES * INPUT_SIZE)   // 401408  windows_y_hat
#define OUT1_N (OUTPUT_SIZE * N_SERIES * OUTPUT_SIZE)  // 100352  windows_y (zeros)
#define LEV_N  (N_SERIES * N_TIME)                     // levels
#define SEA_N  (N_SERIES * (N_TIME + SEAS))            // seasonalities

#define LCH  112        // main steps owned per chunk (16*7)
#define WUP  224        // guess-warmup steps (32 season cycles)
#define NCH  37         // chunks: t0(c) = 1 + 112c; c=36 owns 4033..4095 (partial)
#define TT   56         // tile steps (8*7 -> season slot j is static)
#define STR  65         // LDS row stride (dwords): scanner bank (lane+k)%32 -> 2-way (free)
#define WSP  (NCH * N_SERIES)   // ws plane stride (floats)
// ws planes: 0=level, 1..7=ring, 8=A(sum log2 ring@chunk end), 9=B(@t0), 10=kappa

__device__ __forceinline__ float rcp_(float x){ return __builtin_amdgcn_rcpf(x); }
__device__ __forceinline__ float log2_(float x){ return __builtin_amdgcn_logf(x); }

// async global->LDS: 4B/lane, LDS dest = base + lane*4 (linear), global src per-lane
#define GLD_LDS(gp, lp)                                                        \
    __builtin_amdgcn_global_load_lds(                                          \
        (const __attribute__((address_space(1))) unsigned int*)(gp),           \
        (__attribute__((address_space(3))) unsigned int*)(lp), 4, 0, 0)

#define WAIT_VM0() asm volatile("s_waitcnt vmcnt(0)" ::: "memory")

// issue 64 row-loads of tile at time tb into lbuf[r][0..63] (lane = time offset)
__device__ __forceinline__ void stage_tile(
    const float* __restrict__ y, int s0, int tb, int lane, float (*lbuf)[STR])
{
    int t = tb + lane; t = (t > N_TIME - 1) ? (N_TIME - 1) : t;   // junk-lane clamp
#pragma unroll 16
    for (int r = 0; r < 64; ++r)
        GLD_LDS(&y[(size_t)(s0 + r) * N_TIME + t], &lbuf[r][0]);
}

// ---------- Stage A: chunked warmup scan, emit scale anchors + state ----------
// c==0: exact main only (2 tiles). c==1: exact 112 wup + main (4). c==2: exact
// 224 wup + main (6). c>=3: guessed 224 wup + main (6 tiles).
__global__ __launch_bounds__(64) void es_stageA(
    const float* __restrict__ y, const int* __restrict__ idxs,
    const float* __restrict__ emb, float* __restrict__ ws)
{
    __shared__ float ly[2][64][STR];   // [buf][series-row][time] 33.3 KB
    const int lane = threadIdx.x;
    const int c = blockIdx.x % NCH, g = blockIdx.x / NCH;
    const int s0 = g * 64, s = s0 + lane;
    const int t0 = 1 + c * LCH;
    const bool exact = (c <= 2);
    const int tw = exact ? 1 : (t0 - WUP);
    const int ntiles = (c == 0) ? 2 : ((c == 1) ? 4 : 6);
    const int save_tt = (c == 1) ? 1 : 3;    // tile after which state@t0 is saved

    // prologue: stage tile 0 into buf 0 (async, overlaps setup below)
    stage_tile(y, s0, tw, lane, ly[0]);

    const float* e = emb + (size_t)idxs[s] * EMB;
    const float lev_sms  = 1.f / (1.f + expf(-e[0]));
    const float seas_sms = 1.f / (1.f + expf(-e[1]));
    const float oml = 1.f - lev_sms, oms = 1.f - seas_sms;

    float ring[7], rsl[7], level;
    if (exact) {
        float einit[7];
#pragma unroll
        for (int j = 0; j < 7; ++j) einit[j] = expf(e[2 + j]);
#pragma unroll
        for (int j = 0; j < 7; ++j) ring[j] = einit[(1 + j) % 7]; // slot j ~ t=(1+j)%7
        level = y[(size_t)s * N_TIME] * rcp_(einit[0]);
    } else {
#pragma unroll
        for (int j = 0; j < 7; ++j) ring[j] = 1.64872127f;   // exp(0.5) prior
        level = y[(size_t)s * N_TIME + (tw - 1)] * 0.60653066f;
    }
#pragma unroll
    for (int j = 0; j < 7; ++j) rsl[j] = lev_sms * rcp_(ring[j]);

    float svlev = 1.f, svring[7];
#pragma unroll
    for (int j = 0; j < 7; ++j) svring[j] = 1.f;

    WAIT_VM0();   // tile 0 resident
    for (int tt = 0; tt < ntiles; ++tt) {
        const int cur = tt & 1;
        // prefetch next tile into the other buffer (fire-and-forget)
        if (tt + 1 < ntiles)
            stage_tile(y, s0, tw + (tt + 1) * TT, lane, ly[cur ^ 1]);
        // scan 56 steps of current tile; k%7==j static (TT mult of 7, tb≡1 mod 7)
        const float* yrow = &ly[cur][lane][0];
        for (int g8 = 0; g8 < 8; ++g8) {
#pragma unroll
            for (int j = 0; j < 7; ++j) {
                const int k = g8 * 7 + j;
                float yt = yrow[k];
                float nl = fmaf(oml, level, yt * rsl[j]);
                float rl = rcp_(nl);
                float ns = fmaf(oms, ring[j], (seas_sms * yt) * rl);
                ring[j] = ns;
                rsl[j]  = lev_sms * rcp_(ns);
                level = nl;
            }
        }
        if (c != 0 && tt == save_tt) {   // state entering step t0
            svlev = level;
#pragma unroll
            for (int j = 0; j < 7; ++j) svring[j] = ring[j];
        }
        WAIT_VM0();   // prefetched tile resident
    }

    float A = 0.f;
#pragma unroll
    for (int j = 0; j < 7; ++j) A += log2_(ring[j]);
    ws[8 * WSP + c * N_SERIES + s] = A;
    if (c != 0) {
        float B = 0.f;
#pragma unroll
        for (int j = 0; j < 7; ++j) B += log2_(svring[j]);
        ws[9 * WSP + c * N_SERIES + s] = B;
        ws[0 * WSP + c * N_SERIES + s] = svlev;
#pragma unroll
        for (int j = 0; j < 7; ++j)
            ws[(1 + j) * WSP + c * N_SERIES + s] = svring[j];
    }
}

// ---------- Chain: per-series kappa over 37 chunks + zero windows_y ----------
__global__ __launch_bounds__(64) void es_chain(float* __restrict__ ws,
                                               float* __restrict__ out1)
{
    const int tid = blockIdx.x * 64 + threadIdx.x;   // 2048 threads
    // zero windows_y (float4, coalesced)
    float4 z4 = {0.f, 0.f, 0.f, 0.f};
    for (int i = tid; i < OUT1_N / 4; i += N_SERIES)
        ((float4*)out1)[i] = z4;

    const int s = tid;
    float kap = 0.f;
    ws[10 * WSP + 0 * N_SERIES + s] = 0.f;
    float Aprev = ws[8 * WSP + 0 * N_SERIES + s];
    for (int c = 1; c < NCH; ++c) {
        float B = ws[9 * WSP + c * N_SERIES + s];
        kap += (Aprev - B) * (1.f / 7.f);
        ws[10 * WSP + c * N_SERIES + s] = kap;
        Aprev = ws[8 * WSP + c * N_SERIES + s];
    }
}

// ---------- Stage C: rescaled re-scan of owned 112 steps, store outputs ----------
__global__ __launch_bounds__(64) void es_stageC(
    const float* __restrict__ y, const int* __restrict__ idxs,
    const float* __restrict__ emb, const float* __restrict__ ws,
    float* __restrict__ levels, float* __restrict__ seas_out)
{
    __shared__ float ly[64][STR], llev[64][STR], lsea[64][STR];  // 50 KB
    const int lane = threadIdx.x;
    const int c = blockIdx.x % NCH, g = blockIdx.x / NCH;
    const int s0 = g * 64, s = s0 + lane;
    const int t0 = 1 + c * LCH;

    stage_tile(y, s0, t0, lane, ly);   // tile 0 async

    const float* e = emb + (size_t)idxs[s] * EMB;
    const float lev_sms  = 1.f / (1.f + expf(-e[0]));
    const float seas_sms = 1.f / (1.f + expf(-e[1]));
    const float oml = 1.f - lev_sms, oms = 1.f - seas_sms;

    float ring[7], rsl[7], level;
    if (c == 0) {
        float einit[7];
#pragma unroll
        for (int j = 0; j < 7; ++j) einit[j] = expf(e[2 + j]);
#pragma unroll
        for (int j = 0; j < 7; ++j) ring[j] = einit[(1 + j) % 7];
        level = y[(size_t)s * N_TIME] * rcp_(einit[0]);
        levels[(size_t)s * N_TIME] = level;              // levels[:,0]
        float* sr = seas_out + (size_t)s * (N_TIME + SEAS);
#pragma unroll
        for (int j = 0; j < 7; ++j) sr[j] = einit[j];    // seasonalities[:,0..6]
        sr[7] = einit[0];                                // seasonalities[:,7]
    } else {
        float kap = ws[10 * WSP + c * N_SERIES + s];
        float f  = exp2f(kap);     // true_sea = our_sea * 2^kappa
        float fi = exp2f(-kap);    // true_lev = our_lev * 2^-kappa
        level = ws[0 * WSP + c * N_SERIES + s] * fi;
#pragma unroll
        for (int j = 0; j < 7; ++j)
            ring[j] = ws[(1 + j) * WSP + c * N_SERIES + s] * f;
    }
#pragma unroll
    for (int j = 0; j < 7; ++j) rsl[j] = lev_sms * rcp_(ring[j]);

    for (int tt = 0; tt < 2; ++tt) {
        const int tb = t0 + tt * TT;
        WAIT_VM0();   // tile tt resident
        // scan 56 steps, record lev/sea into LDS [series-row][time]
        const float* yrow = &ly[lane][0];
        float* lrow = &llev[lane][0];
        float* srow = &lsea[lane][0];
        for (int g8 = 0; g8 < 8; ++g8) {
#pragma unroll
            for (int j = 0; j < 7; ++j) {
                const int k = g8 * 7 + j;
                float yt = yrow[k];
                float nl = fmaf(oml, level, yt * rsl[j]);
                float rl = rcp_(nl);
                float ns = fmaf(oms, ring[j], (seas_sms * yt) * rl);
                ring[j] = ns;
                rsl[j]  = lev_sms * rcp_(ns);
                lrow[k] = nl;
                srow[k] = ns;
                level = nl;
            }
        }
        // prefetch tile 1 AFTER scan (ly is single-buffered; overlap writeback)
        if (tt == 0)
            stage_tile(y, s0, t0 + TT, lane, ly);
        // transpose-writeback: coalesced stores along time (lane = time)
        if (lane < TT) {
            const int t = tb + lane;
            if (t <= N_TIME - 1) {
#pragma unroll 8
                for (int r = 0; r < 64; ++r) {
                    levels[(size_t)(s0 + r) * N_TIME + t] = llev[r][lane];
                    seas_out[(size_t)(s0 + r) * (N_TIME + SEAS) + SEAS + t] = lsea[r][lane];
                }
            }
        }
    }
}

// ---------- windows_y_hat ----------
__global__ __launch_bounds__(256) void es_windows(
    const float* __restrict__ y,
    const float* __restrict__ levels,
    const float* __restrict__ seas,
    float* __restrict__ out0)
{
    int tid = blockIdx.x * 256 + threadIdx.x;
    int i = tid % INPUT_SIZE;
    int r = tid / INPUT_SIZE;
    int s = r & (N_SERIES - 1);
    int w = r >> 11;
    int t = (N_TIME - INPUT_SIZE - OUTPUT_SIZE + 1) + w + i;     // 4062+w+i
    float yt = y[(size_t)s * N_TIME + t];
    float lv = levels[(size_t)s * N_TIME + (N_TIME - OUTPUT_SIZE + w)];
    float sv = seas[(size_t)s * (N_TIME + SEAS) + t];
    float ratio = yt * rcp_(lv * sv);
    out0[tid] = log2_(ratio) * 0.6931471805599453f;   // ln = log2 * ln2
}

extern "C" void kernel_launch(void* const* d_in, const int* in_sizes, int n_in,
                              void* d_out, int out_size, void* d_ws, size_t ws_size,
                              hipStream_t stream) {
    const float* y    = (const float*)d_in[0];
    const int*   idxs = (const int*)d_in[1];
    const float* emb  = (const float*)d_in[2];

    float* out  = (float*)d_out;
    float* out0 = out;                           // windows_y_hat
    float* out1 = out + OUT0_N;                  // windows_y (zeros)
    float* lev  = out + OUT0_N + OUT1_N;         // levels
    float* sea  = out + OUT0_N + OUT1_N + LEV_N; // seasonalities
    float* ws   = (float*)d_ws;                  // 11 planes * 37*2048 floats ≈ 3.3 MB

    es_stageA<<<32 * NCH, 64, 0, stream>>>(y, idxs, emb, ws);
    es_chain<<<N_SERIES / 64, 64, 0, stream>>>(ws, out1);
    es_stageC<<<32 * NCH, 64, 0, stream>>>(y, idxs, emb, ws, lev, sea);
    es_windows<<<OUT0_N / 256, 256, 0, stream>>>(y, lev, sea, out0);
}